// Round 16
// baseline (23.447 us; speedup 1.0000x reference)
//
#include <hip/hip_runtime.h>
#include <hip/hip_bf16.h>
#include <math.h>

// Problem constants (fixed by setup_inputs): B=8, M=256, D=768, K=100
#define NROWS 2048
#define DDIM  768
#define TNB   384        // fp4 row bytes (768 * 0.5)
#define KNEG  100
#define NLOGITS 101
#define MT 7             // 7 M-tiles of 16 logits (112 padded slots)

typedef __attribute__((ext_vector_type(4))) float floatx4;
typedef __attribute__((ext_vector_type(4))) int   intx4;
typedef __attribute__((ext_vector_type(8))) int   intx8;

static constexpr float LFAC = 10.0f / 32.0f;  // TEMP_INV / fp4 prescale
static constexpr float EPS_NORM = 1e-8f;

__device__ __forceinline__ unsigned pack_fp8x4(float a, float b, float c, float d) {
    int u = 0;
    u = __builtin_amdgcn_cvt_pk_fp8_f32(a, b, u, false);
    u = __builtin_amdgcn_cvt_pk_fp8_f32(c, d, u, true);
    return (unsigned)u;
}

// quantize pre-scaled v to fp4 e2m1 nibble, round-to-nearest
__device__ __forceinline__ unsigned fp4n(float v) {
    const float a = fminf(fabsf(v), 6.0f);
    const unsigned c = (a >= 0.25f) + (a >= 0.75f) + (a >= 1.25f) + (a >= 1.75f)
                     + (a >= 2.5f)  + (a >= 3.5f)  + (a >= 5.0f);
    return c | (v < 0.f ? 8u : 0u);
}

// Kernel 1: normalize target rows, quantize to fp4 e2m1 (x32 prescale).
// tn4 = 768 KB total; L2-resident gather source. One wave per row.
__global__ __launch_bounds__(256) void cl_prep_kernel(
        const float* __restrict__ targets,
        unsigned char* __restrict__ tn4) {
    const int wave = threadIdx.x >> 6, lane = threadIdx.x & 63;
    const int row = blockIdx.x * 4 + wave;
    const float4* tv = (const float4*)(targets + (size_t)row * DDIM);
    const float4 a0 = tv[2 * lane], a1 = tv[2 * lane + 1], b0 = tv[128 + lane];

    float ss = 0.f;
    ss = fmaf(a0.x, a0.x, ss); ss = fmaf(a0.y, a0.y, ss);
    ss = fmaf(a0.z, a0.z, ss); ss = fmaf(a0.w, a0.w, ss);
    ss = fmaf(a1.x, a1.x, ss); ss = fmaf(a1.y, a1.y, ss);
    ss = fmaf(a1.z, a1.z, ss); ss = fmaf(a1.w, a1.w, ss);
    ss = fmaf(b0.x, b0.x, ss); ss = fmaf(b0.y, b0.y, ss);
    ss = fmaf(b0.z, b0.z, ss); ss = fmaf(b0.w, b0.w, ss);
    #pragma unroll
    for (int off = 32; off > 0; off >>= 1) ss += __shfl_xor(ss, off);
    const float sc = 32.0f / fmaxf(sqrtf(ss), EPS_NORM);   // normalize + x32

    const unsigned ua =  fp4n(a0.x * sc)        | (fp4n(a0.y * sc) << 4)
                      | (fp4n(a0.z * sc) << 8)  | (fp4n(a0.w * sc) << 12)
                      | (fp4n(a1.x * sc) << 16) | (fp4n(a1.y * sc) << 20)
                      | (fp4n(a1.z * sc) << 24) | (fp4n(a1.w * sc) << 28);
    const unsigned short ub = (unsigned short)(fp4n(b0.x * sc)
                      | (fp4n(b0.y * sc) << 4) | (fp4n(b0.z * sc) << 8)
                      | (fp4n(b0.w * sc) << 12));

    __shared__ __align__(16) unsigned char buf[4][TNB];
    *(unsigned*)(&buf[wave][4 * lane]) = ua;
    *(unsigned short*)(&buf[wave][256 + 2 * lane]) = ub;
    __syncthreads();
    if (lane < 24)
        ((uint4*)(tn4 + (size_t)row * TNB))[lane] = *(const uint4*)(&buf[wave][16 * lane]);
}

// Kernel 2: one block (4 waves) per pred row. ALL 4 supertiles of fp4 target
// rows DMA'd to LDS in the prologue (4 buffers, latency hides under pred
// normalize); K-loop = counted vmcnt(8/5/2/0) + one barrier per supertile,
// zero staging, zero trailing barriers. MFMA = mfma_scale 16x16x128 f8f6f4,
// A=fp4 targets, B=fp8 pred (identity scales; /32 folded into LFAC).
__global__ __launch_bounds__(256, 3) void cl_rowloss_kernel(
        const float* __restrict__ preds,
        const unsigned char* __restrict__ tn4,
        const int* __restrict__ neg_idx,
        float* __restrict__ row_loss) {
    const int i = blockIdx.x;
    const int tid = threadIdx.x;
    const int wave = tid >> 6, lane = tid & 63;
    const int khalf = wave & 1, thalf = wave >> 1;
    const int q = lane >> 4, rr = lane & 15;

    __shared__ __align__(16) unsigned char Ab[4][32 * TNB];  // 4 x 12 KB
    __shared__ __align__(16) unsigned char pn8[DDIM];        // pred, fp8
    __shared__ __align__(16) float parts[2][MT * 16];        // per-khalf partials
    __shared__ int idx_lds[MT * 16];
    __shared__ float sP[3];

    if (tid < MT * 16)
        idx_lds[tid] = (tid == 0 || tid > KNEG) ? i : neg_idx[(size_t)i * KNEG + tid - 1];
    __syncthreads();

    // Supertile s = tiles {s, s+4}: 32 rows x 384B = 768 x 16B chunks.
    // LDS dest linear (chunk g at byte 16g); source chunk XOR-swizzled
    // (c ^ (rl&7)) so the swizzled ds_reads below see logical data (rule #21).
    // s=3: 512 chunks (tile 3 = rows 0-15; rows 16-21 are uniform pad reading
    // slot 0 -- keeps DMA count wave-uniform; pad region never read).
    auto stage = [&](int s, int nchunk) {
        #pragma unroll
        for (int it = 0; it < 3; ++it) {
            const int g = it * 256 + wave * 64 + lane;
            if (g < nchunk) {
                const int rl = g / 24, c = g - rl * 24;      // row 0..31, chunk 0..23
                const int slot = (rl < 16) ? s * 16 + rl
                                 : (s < 3 ? s * 16 + rl + 48 : 0);
                const unsigned char* src = tn4 + (size_t)idx_lds[slot] * TNB
                                           + ((c ^ (rl & 7)) << 4);
                __builtin_amdgcn_global_load_lds(
                    (const __attribute__((address_space(1))) void*)src,
                    (__attribute__((address_space(3))) void*)&Ab[s][(it * 256 + wave * 64) << 4],
                    16, 0, 0);
            }
        }
    };

    // pred loads first (oldest in vmcnt FIFO: retire before staging loads)
    float4 pv4;
    if (tid < 192) pv4 = ((const float4*)(preds + (size_t)i * DDIM))[tid];

    // ALL supertiles in flight: 3+3+3+2 = 11 DMA/wave
    stage(0, 768);
    stage(1, 768);
    stage(2, 768);
    stage(3, 512);

    // pred normalize under DMA latency (compiler waits only the pred float4)
    if (tid < 192) {
        float ss = fmaf(pv4.x, pv4.x, fmaf(pv4.y, pv4.y,
                   fmaf(pv4.z, pv4.z, pv4.w * pv4.w)));
        #pragma unroll
        for (int off = 32; off > 0; off >>= 1) ss += __shfl_xor(ss, off);
        if (lane == 0) sP[wave] = ss;
    }
    asm volatile("s_waitcnt lgkmcnt(0)" ::: "memory");
    __builtin_amdgcn_s_barrier();
    __builtin_amdgcn_sched_barrier(0);
    if (tid < 192) {
        const float inv = 1.0f / fmaxf(sqrtf(sP[0] + sP[1] + sP[2]), EPS_NORM);
        ((unsigned*)pn8)[tid] = pack_fp8x4(pv4.x * inv, pv4.y * inv,
                                           pv4.z * inv, pv4.w * inv);
    }
    asm volatile("s_waitcnt lgkmcnt(0)" ::: "memory");
    __builtin_amdgcn_s_barrier();
    __builtin_amdgcn_sched_barrier(0);

    // B-frags (pred fp8): 3 MFMAs x 32B, lane holds k = khalf*384 + m*128 + q*32
    intx8 b8[3];
    #pragma unroll
    for (int m = 0; m < 3; ++m) {
        const int boff = khalf * 384 + m * 128 + q * 32;
        const intx4 lo = *(const intx4*)(&pn8[boff]);
        const intx4 hi = *(const intx4*)(&pn8[boff + 16]);
        b8[m] = (intx8){lo.x, lo.y, lo.z, lo.w, hi.x, hi.y, hi.z, hi.w};
    }

    floatx4 acc[4] = {};
    const int rbase = (thalf * 16 + rr) * TNB;   // A row within 32-row buffer
    const int rx = rr & 7;                        // swizzle key (row & 7)

    // K-loop: per supertile S -- counted vmcnt (own loads for S done: FIFO
    // positions uniform across waves incl. the early pred load), barrier
    // (=> ALL waves' S-loads done), 3 MFMAs. No staging, no trailing barrier
    // (buffers are write-once). thalf=1 skips S=3 (tile 7 absent).
#define CL_S(S, NWAIT)                                                        \
    {                                                                         \
        asm volatile("s_waitcnt vmcnt(" #NWAIT ")" ::: "memory");             \
        __builtin_amdgcn_s_barrier();                                         \
        __builtin_amdgcn_sched_barrier(0);                                    \
        if (!thalf || (S) < 3) {                                              \
            _Pragma("unroll")                                                 \
            for (int m = 0; m < 3; ++m) {                                     \
                const int cl = khalf * 12 + m * 4 + q;                        \
                const intx4 a4 = *(const intx4*)(&Ab[S][rbase + ((cl ^ rx) << 4)]); \
                const intx8 a8 = (intx8){a4.x, a4.y, a4.z, a4.w, 0, 0, 0, 0}; \
                acc[S] = __builtin_amdgcn_mfma_scale_f32_16x16x128_f8f6f4(    \
                    a8, b8[m], acc[S], 4 /*A=fp4*/, 0 /*B=fp8*/,              \
                    0, 127, 0, 127);                                          \
            }                                                                 \
        }                                                                     \
    }

    CL_S(0, 8)
    CL_S(1, 5)
    CL_S(2, 2)
    CL_S(3, 0)
#undef CL_S

    // partial dots -> LDS. C/D map: col=lane&15, row=(lane>>4)*4+reg
    if (rr == 0) {
        const int rb = q * 4;
        if (!thalf) {
            #pragma unroll
            for (int t = 0; t < 4; ++t)
                *(floatx4*)(&parts[khalf][t * 16 + rb]) = acc[t];
        } else {
            #pragma unroll
            for (int t = 0; t < 3; ++t)
                *(floatx4*)(&parts[khalf][(t + 4) * 16 + rb]) = acc[t];
        }
    }
    __syncthreads();

    // wave 0: combine K-halves, logsumexp over logits[0..100]
    if (wave == 0) {
        const float v0 = (parts[0][lane] + parts[1][lane]) * LFAC;
        float v1 = -INFINITY;
        if (lane <= NLOGITS - 65)
            v1 = (parts[0][64 + lane] + parts[1][64 + lane]) * LFAC;
        const float l0 = __shfl(v0, 0);
        float m = fmaxf(v0, v1);
        #pragma unroll
        for (int off = 32; off > 0; off >>= 1) m = fmaxf(m, __shfl_xor(m, off));
        float e = expf(v0 - m);
        if (lane <= NLOGITS - 65) e += expf(v1 - m);
        #pragma unroll
        for (int off = 32; off > 0; off >>= 1) e += __shfl_xor(e, off);
        if (lane == 0) row_loss[i] = (m + logf(e)) - l0;
    }
}

// Kernel 3: deterministic final mean over the 2048 row losses.
__global__ void cl_reduce_kernel(const float* __restrict__ row_loss,
                                 float* __restrict__ out) {
    const int tid = threadIdx.x; // 256
    float s = 0.f;
    #pragma unroll
    for (int c = 0; c < 2; ++c) {
        const float4 v = ((const float4*)row_loss)[tid + 256 * c];
        s += (v.x + v.y) + (v.z + v.w);
    }
    #pragma unroll
    for (int off = 32; off > 0; off >>= 1) s += __shfl_down(s, off);
    __shared__ float sw[4];
    const int wave = tid >> 6, lane = tid & 63;
    if (lane == 0) sw[wave] = s;
    __syncthreads();
    if (tid == 0) out[0] = (sw[0] + sw[1] + sw[2] + sw[3]) / (float)NROWS;
}

extern "C" void kernel_launch(void* const* d_in, const int* in_sizes, int n_in,
                              void* d_out, int out_size, void* d_ws, size_t ws_size,
                              hipStream_t stream) {
    const float* preds   = (const float*)d_in[0];
    const float* targets = (const float*)d_in[1];
    const int*   neg_idx = (const int*)d_in[2];
    float* out = (float*)d_out;

    // workspace: tn4 (768 KB) | row_loss[2048]
    unsigned char* tn4 = (unsigned char*)d_ws;
    float* row_loss = (float*)((char*)d_ws + (size_t)NROWS * TNB);

    cl_prep_kernel<<<NROWS / 4, 256, 0, stream>>>(targets, tn4);
    cl_rowloss_kernel<<<NROWS, 256, 0, stream>>>(preds, tn4, neg_idx, row_loss);
    cl_reduce_kernel<<<1, 256, 0, stream>>>(row_loss, out);
}

// Round 17
// 21.206 us; speedup vs baseline: 1.1057x; 1.1057x over previous
//
#include <hip/hip_runtime.h>
#include <hip/hip_bf16.h>
#include <math.h>

// Problem constants (fixed by setup_inputs): B=8, M=256, D=768, K=100
#define NROWS 2048
#define DDIM  768
#define TNB   384        // fp4 row bytes (768 * 0.5)
#define KNEG  100
#define NLOGITS 101
#define MT 7             // 7 M-tiles of 16 logits (112 padded slots)

typedef __attribute__((ext_vector_type(4))) float floatx4;
typedef __attribute__((ext_vector_type(4))) int   intx4;
typedef __attribute__((ext_vector_type(8))) int   intx8;

static constexpr float LFAC = 10.0f / 32.0f;  // TEMP_INV / fp4 prescale
static constexpr float EPS_NORM = 1e-8f;

__device__ __forceinline__ unsigned pack_fp8x4(float a, float b, float c, float d) {
    int u = 0;
    u = __builtin_amdgcn_cvt_pk_fp8_f32(a, b, u, false);
    u = __builtin_amdgcn_cvt_pk_fp8_f32(c, d, u, true);
    return (unsigned)u;
}

// quantize pre-scaled v to fp4 e2m1 nibble, round-to-nearest
// codes: 0,0.5,1,1.5,2,3,4,6 ; midpoints .25,.75,1.25,1.75,2.5,3.5,5
__device__ __forceinline__ unsigned fp4n(float v) {
    const float a = fminf(fabsf(v), 6.0f);
    const unsigned c = (a >= 0.25f) + (a >= 0.75f) + (a >= 1.25f) + (a >= 1.75f)
                     + (a >= 2.5f)  + (a >= 3.5f)  + (a >= 5.0f);
    return c | (v < 0.f ? 8u : 0u);
}

// Kernel 1: normalize target rows, quantize to fp4 e2m1 (x32 prescale).
// tn4 = 768 KB total; L2-resident gather source. One wave per row.
__global__ __launch_bounds__(256) void cl_prep_kernel(
        const float* __restrict__ targets,
        unsigned char* __restrict__ tn4) {
    const int wave = threadIdx.x >> 6, lane = threadIdx.x & 63;
    const int row = blockIdx.x * 4 + wave;
    const float4* tv = (const float4*)(targets + (size_t)row * DDIM);
    const float4 a0 = tv[2 * lane], a1 = tv[2 * lane + 1], b0 = tv[128 + lane];

    float ss = 0.f;
    ss = fmaf(a0.x, a0.x, ss); ss = fmaf(a0.y, a0.y, ss);
    ss = fmaf(a0.z, a0.z, ss); ss = fmaf(a0.w, a0.w, ss);
    ss = fmaf(a1.x, a1.x, ss); ss = fmaf(a1.y, a1.y, ss);
    ss = fmaf(a1.z, a1.z, ss); ss = fmaf(a1.w, a1.w, ss);
    ss = fmaf(b0.x, b0.x, ss); ss = fmaf(b0.y, b0.y, ss);
    ss = fmaf(b0.z, b0.z, ss); ss = fmaf(b0.w, b0.w, ss);
    #pragma unroll
    for (int off = 32; off > 0; off >>= 1) ss += __shfl_xor(ss, off);
    const float sc = 32.0f / fmaxf(sqrtf(ss), EPS_NORM);   // normalize + x32

    // dims 8l..8l+7 -> 8 nibbles -> u32 at byte 4l; dims 512+4l.. -> u16
    const unsigned ua =  fp4n(a0.x * sc)        | (fp4n(a0.y * sc) << 4)
                      | (fp4n(a0.z * sc) << 8)  | (fp4n(a0.w * sc) << 12)
                      | (fp4n(a1.x * sc) << 16) | (fp4n(a1.y * sc) << 20)
                      | (fp4n(a1.z * sc) << 24) | (fp4n(a1.w * sc) << 28);
    const unsigned short ub = (unsigned short)(fp4n(b0.x * sc)
                      | (fp4n(b0.y * sc) << 4) | (fp4n(b0.z * sc) << 8)
                      | (fp4n(b0.w * sc) << 12));

    __shared__ __align__(16) unsigned char buf[4][TNB];
    *(unsigned*)(&buf[wave][4 * lane]) = ua;
    *(unsigned short*)(&buf[wave][256 + 2 * lane]) = ub;
    __syncthreads();
    if (lane < 24)
        ((uint4*)(tn4 + (size_t)row * TNB))[lane] = *(const uint4*)(&buf[wave][16 * lane]);
}

// Kernel 2: one block (4 waves) per pred row. fp4 target rows DMA'd to LDS
// in 32-row supertiles {t, t+4} (double-buffered, XOR-swizzled source,
// rule #21). MFMA = mfma_scale 16x16x128 f8f6f4, A=fp4 targets, B=fp8 pred
// (identity scales; /32 folded into LFAC). Waves: khalf=wave&1 (K 0/384),
// thalf=wave>>1 (tiles 0-3 / 4-6). Wave 0 logsumexp.
__global__ __launch_bounds__(256, 5) void cl_rowloss_kernel(
        const float* __restrict__ preds,
        const unsigned char* __restrict__ tn4,
        const int* __restrict__ neg_idx,
        float* __restrict__ row_loss) {
    const int i = blockIdx.x;
    const int tid = threadIdx.x;
    const int wave = tid >> 6, lane = tid & 63;
    const int khalf = wave & 1, thalf = wave >> 1;
    const int q = lane >> 4, rr = lane & 15;

    __shared__ __align__(16) unsigned char Ab[2][32 * TNB];  // 2 x 12 KB
    __shared__ __align__(16) unsigned char pn8[DDIM];        // pred, fp8
    __shared__ __align__(16) float parts[2][MT * 16];        // per-khalf partials
    __shared__ int idx_lds[MT * 16];
    __shared__ float sP[3];

    if (tid < MT * 16)
        idx_lds[tid] = (tid == 0 || tid > KNEG) ? i : neg_idx[(size_t)i * KNEG + tid - 1];
    __syncthreads();

    // Supertile s = tiles {s, s+4}: 32 rows x 384B = 768 x 16B chunks.
    // LDS dest linear (chunk g at byte 16g); source chunk XOR-swizzled
    // (c ^ (rl&7)) so the swizzled ds_reads below see logical data.
    auto stage = [&](int s, int buf, int nchunk) {
        #pragma unroll
        for (int it = 0; it < 3; ++it) {
            const int g = it * 256 + wave * 64 + lane;
            if (g < nchunk) {
                const int rl = g / 24, c = g - rl * 24;      // row 0..31, chunk 0..23
                const int slot = s * 16 + (rl < 16 ? rl : rl + 48);
                const unsigned char* src = tn4 + (size_t)idx_lds[slot] * TNB
                                           + ((c ^ (rl & 7)) << 4);
                __builtin_amdgcn_global_load_lds(
                    (const __attribute__((address_space(1))) void*)src,
                    (__attribute__((address_space(3))) void*)&Ab[buf][(it * 256 + wave * 64) << 4],
                    16, 0, 0);
            }
        }
    };

    // pred loads first (oldest in vmcnt FIFO), then supertile 0 in flight
    float4 pv4;
    if (tid < 192) pv4 = ((const float4*)(preds + (size_t)i * DDIM))[tid];
    stage(0, 0, 768);

    if (tid < 192) {
        float ss = fmaf(pv4.x, pv4.x, fmaf(pv4.y, pv4.y,
                   fmaf(pv4.z, pv4.z, pv4.w * pv4.w)));
        #pragma unroll
        for (int off = 32; off > 0; off >>= 1) ss += __shfl_xor(ss, off);
        if (lane == 0) sP[wave] = ss;
    }
    asm volatile("s_waitcnt lgkmcnt(0)" ::: "memory");
    __builtin_amdgcn_s_barrier();
    __builtin_amdgcn_sched_barrier(0);
    if (tid < 192) {
        const float inv = 1.0f / fmaxf(sqrtf(sP[0] + sP[1] + sP[2]), EPS_NORM);
        ((unsigned*)pn8)[tid] = pack_fp8x4(pv4.x * inv, pv4.y * inv,
                                           pv4.z * inv, pv4.w * inv);
    }
    __syncthreads();   // pn8 ready AND supertile 0 resident (full drain)

    // B-frags (pred fp8): 3 MFMAs x 32B, lane holds k = kbase + q*32 .. +32
    intx8 b8[3];
    #pragma unroll
    for (int m = 0; m < 3; ++m) {
        const int boff = khalf * 384 + m * 128 + q * 32;
        const intx4 lo = *(const intx4*)(&pn8[boff]);
        const intx4 hi = *(const intx4*)(&pn8[boff + 16]);
        b8[m] = (intx8){lo.x, lo.y, lo.z, lo.w, hi.x, hi.y, hi.z, hi.w};
    }

    floatx4 acc[4] = {};
    const int rbase = (thalf * 16 + rr) * TNB;   // A row within 32-row buffer
    const int rx = rr & 7;                        // swizzle key (row & 7)

    // Iteration S: (optionally) stage supertile S+1, compute this wave's
    // tile of supertile S (3 MFMAs, K=128 each), barrier (drains DMA +
    // protects buffer reuse). thalf1 has no tile at S=3 (tile 7 absent).
#define CL_S(S, NC_NEXT, DO_STAGE)                                            \
    {                                                                         \
        if (DO_STAGE) stage((S) + 1, ((S) + 1) & 1, NC_NEXT);                 \
        if (!thalf || (S) < 3) {                                              \
            _Pragma("unroll")                                                 \
            for (int m = 0; m < 3; ++m) {                                     \
                const int cl = khalf * 12 + m * 4 + q;                        \
                const intx4 a4 = *(const intx4*)(&Ab[(S) & 1][rbase + ((cl ^ rx) << 4)]); \
                const intx8 a8 = (intx8){a4.x, a4.y, a4.z, a4.w, 0, 0, 0, 0}; \
                acc[S] = __builtin_amdgcn_mfma_scale_f32_16x16x128_f8f6f4(    \
                    a8, b8[m], acc[S], 4 /*A=fp4*/, 0 /*B=fp8*/,              \
                    0, 127, 0, 127);                                          \
            }                                                                 \
        }                                                                     \
        __syncthreads();                                                      \
    }

    CL_S(0, 768, 1)
    CL_S(1, 768, 1)
    CL_S(2, 384, 1)   // supertile 3 = tile 3 only (16 rows, 384 chunks)
    CL_S(3, 0, 0)
#undef CL_S

    // partial dots -> LDS. C/D map: col=lane&15, row=(lane>>4)*4+reg
    if (rr == 0) {
        const int rb = q * 4;
        if (!thalf) {
            #pragma unroll
            for (int t = 0; t < 4; ++t)
                *(floatx4*)(&parts[khalf][t * 16 + rb]) = acc[t];
        } else {
            #pragma unroll
            for (int t = 0; t < 3; ++t)
                *(floatx4*)(&parts[khalf][(t + 4) * 16 + rb]) = acc[t];
        }
    }
    __syncthreads();

    // wave 0: combine K-halves, logsumexp over logits[0..100]
    if (wave == 0) {
        const float v0 = (parts[0][lane] + parts[1][lane]) * LFAC;
        float v1 = -INFINITY;
        if (lane <= NLOGITS - 65)
            v1 = (parts[0][64 + lane] + parts[1][64 + lane]) * LFAC;
        const float l0 = __shfl(v0, 0);
        float m = fmaxf(v0, v1);
        #pragma unroll
        for (int off = 32; off > 0; off >>= 1) m = fmaxf(m, __shfl_xor(m, off));
        float e = expf(v0 - m);
        if (lane <= NLOGITS - 65) e += expf(v1 - m);
        #pragma unroll
        for (int off = 32; off > 0; off >>= 1) e += __shfl_xor(e, off);
        if (lane == 0) row_loss[i] = (m + logf(e)) - l0;
    }
}

// Kernel 3: deterministic final mean over the 2048 row losses.
__global__ void cl_reduce_kernel(const float* __restrict__ row_loss,
                                 float* __restrict__ out) {
    const int tid = threadIdx.x; // 256
    float s = 0.f;
    #pragma unroll
    for (int c = 0; c < 2; ++c) {
        const float4 v = ((const float4*)row_loss)[tid + 256 * c];
        s += (v.x + v.y) + (v.z + v.w);
    }
    #pragma unroll
    for (int off = 32; off > 0; off >>= 1) s += __shfl_down(s, off);
    __shared__ float sw[4];
    const int wave = tid >> 6, lane = tid & 63;
    if (lane == 0) sw[wave] = s;
    __syncthreads();
    if (tid == 0) out[0] = (sw[0] + sw[1] + sw[2] + sw[3]) / (float)NROWS;
}

extern "C" void kernel_launch(void* const* d_in, const int* in_sizes, int n_in,
                              void* d_out, int out_size, void* d_ws, size_t ws_size,
                              hipStream_t stream) {
    const float* preds   = (const float*)d_in[0];
    const float* targets = (const float*)d_in[1];
    const int*   neg_idx = (const int*)d_in[2];
    float* out = (float*)d_out;

    // workspace: tn4 (768 KB) | row_loss[2048]
    unsigned char* tn4 = (unsigned char*)d_ws;
    float* row_loss = (float*)((char*)d_ws + (size_t)NROWS * TNB);

    cl_prep_kernel<<<NROWS / 4, 256, 0, stream>>>(targets, tn4);
    cl_rowloss_kernel<<<NROWS, 256, 0, stream>>>(preds, tn4, neg_idx, row_loss);
    cl_reduce_kernel<<<1, 256, 0, stream>>>(row_loss, out);
}